// Round 4
// baseline (533.885 us; speedup 1.0000x reference)
//
#include <hip/hip_runtime.h>

// Problem constants (B=8, S=4096, D=64, ds=16)
#define BATCH   8
#define SEQ     4096
#define DM      64
#define DS      16
#define BS      (BATCH*SEQ)      // 32768 timesteps
#define CHUNK   32               // scan chunk length
#define NCH     (SEQ/CHUNK)      // 128 chunks per batch
#define NCH_TOT (BATCH*NCH)      // 1024 chunks total

// ---------------------------------------------------------------------------
// K1: lane = timestep, x-row in registers, weights via wave-uniform s_load.
// Grid 1024: tile = blk>>1, q = blk&1.  4 waves/block; wave w computes
// A j-cols [q*128+w*32, +32) and Bx n = q*8+w*2+{0,1}.  No LDS, no barriers.
// ---------------------------------------------------------------------------
__global__ __launch_bounds__(256, 4) void k1_params(
    const float* __restrict__ x,
    const float* __restrict__ WA, const float* __restrict__ bA,
    const float* __restrict__ WB, const float* __restrict__ bB,
    float* __restrict__ A_ws, float* __restrict__ Bx_ws)
{
  const int tid  = threadIdx.x;
  const int L    = tid & 63;
  const int w    = __builtin_amdgcn_readfirstlane(tid >> 6);
  const int tile = blockIdx.x >> 1;
  const int q    = blockIdx.x & 1;
  const int tt   = tile * 64 + L;

  // x row of this lane's timestep -> registers
  float xr[64];
  {
    const float4* xg = (const float4*)(x + (size_t)tt * DM);
    #pragma unroll
    for (int i = 0; i < 16; ++i) {
      float4 v = xg[i];
      xr[4*i+0] = v.x; xr[4*i+1] = v.y; xr[4*i+2] = v.z; xr[4*i+3] = v.w;
    }
  }

  // ---- A part: 32 j-cols in two 16-wide tiles ----
  const int j0 = q * 128 + w * 32;
  #pragma unroll 1
  for (int jt = 0; jt < 2; ++jt) {
    const int jb = j0 + jt * 16;
    float acc[16];
    #pragma unroll
    for (int k = 0; k < 16; ++k) acc[k] = bA[jb + k];
    #pragma unroll 4
    for (int e = 0; e < 64; ++e) {
      const float* wr = WA + e * 256 + jb;      // wave-uniform -> s_load
      const float xe = xr[e];
      #pragma unroll
      for (int k = 0; k < 16; ++k) acc[k] = fmaf(xe, wr[k], acc[k]);
    }
    float* dst = A_ws + (size_t)tt * 256 + jb;
    #pragma unroll
    for (int p = 0; p < 4; ++p)
      ((float4*)dst)[p] = make_float4(acc[4*p], acc[4*p+1], acc[4*p+2], acc[4*p+3]);
  }

  // ---- Bx part: bx = sum_e x_e (sum_d x_d W[e,n,d]) + sum_d x_d b[n,d] ----
  #pragma unroll 1
  for (int nn = 0; nn < 2; ++nn) {
    const int n = q * 8 + w * 2 + nn;
    const float* bb = bB + n * 64;              // uniform
    float bp0 = 0.f, bp1 = 0.f, bp2 = 0.f, bp3 = 0.f;
    #pragma unroll
    for (int d = 0; d < 16; ++d) {              // bias dot
      bp0 = fmaf(xr[4*d+0], bb[4*d+0], bp0);
      bp1 = fmaf(xr[4*d+1], bb[4*d+1], bp1);
      bp2 = fmaf(xr[4*d+2], bb[4*d+2], bp2);
      bp3 = fmaf(xr[4*d+3], bb[4*d+3], bp3);
    }
    #pragma unroll 2
    for (int e = 0; e < 64; ++e) {
      const float* wr = WB + e * 1024 + n * 64; // uniform
      float s0 = 0.f, s1 = 0.f, s2 = 0.f, s3 = 0.f;
      #pragma unroll
      for (int d = 0; d < 16; ++d) {
        s0 = fmaf(xr[4*d+0], wr[4*d+0], s0);
        s1 = fmaf(xr[4*d+1], wr[4*d+1], s1);
        s2 = fmaf(xr[4*d+2], wr[4*d+2], s2);
        s3 = fmaf(xr[4*d+3], wr[4*d+3], s3);
      }
      const float s = (s0 + s1) + (s2 + s3);
      switch (e & 3) {
        case 0: bp0 = fmaf(xr[e], s, bp0); break;
        case 1: bp1 = fmaf(xr[e], s, bp1); break;
        case 2: bp2 = fmaf(xr[e], s, bp2); break;
        default: bp3 = fmaf(xr[e], s, bp3); break;
      }
    }
    Bx_ws[(size_t)tt * DS + n] = (bp0 + bp1) + (bp2 + bp3);
  }
}

// ---------------------------------------------------------------------------
// K2: per-chunk cumulative transition with ONE barrier per step.
// P/v double-buffered in LDS; A rows read from global (vmcnt, no barrier).
// 256 thr (thread = (i,j)), one block per chunk, grid 1024 -> 4 blocks/CU.
// ---------------------------------------------------------------------------
__global__ __launch_bounds__(256) void k2_chunk(
    const float* __restrict__ A_ws, const float* __restrict__ Bx_ws,
    float* __restrict__ P_ws, float* __restrict__ v_ws)
{
  __shared__ float Ps[2][16][17];   // +1 pad
  __shared__ float vs[2][16];
  const int tid = threadIdx.x;
  const int i = tid >> 4, j = tid & 15;
  const int chunk = blockIdx.x;
  const int tbase = chunk * CHUNK;

  Ps[0][i][j] = (i == j) ? 1.f : 0.f;
  if (tid < 16) vs[0][tid] = 0.f;
  __syncthreads();

  int cur = 0;
  for (int t = 0; t < CHUNK; ++t) {
    const float4* ar = (const float4*)(A_ws + (size_t)(tbase + t) * 256 + i * 16);
    float4 a0 = ar[0], a1 = ar[1], a2 = ar[2], a3 = ar[3];
    float bx = (j == 0) ? Bx_ws[(size_t)(tbase + t) * DS + i] : 0.f;

    float acc;
    acc  = a0.x*Ps[cur][ 0][j] + a0.y*Ps[cur][ 1][j] + a0.z*Ps[cur][ 2][j] + a0.w*Ps[cur][ 3][j];
    acc += a1.x*Ps[cur][ 4][j] + a1.y*Ps[cur][ 5][j] + a1.z*Ps[cur][ 6][j] + a1.w*Ps[cur][ 7][j];
    acc += a2.x*Ps[cur][ 8][j] + a2.y*Ps[cur][ 9][j] + a2.z*Ps[cur][10][j] + a2.w*Ps[cur][11][j];
    acc += a3.x*Ps[cur][12][j] + a3.y*Ps[cur][13][j] + a3.z*Ps[cur][14][j] + a3.w*Ps[cur][15][j];
    float vacc = 0.f;
    if (j == 0) {
      vacc  = a0.x*vs[cur][ 0] + a0.y*vs[cur][ 1] + a0.z*vs[cur][ 2] + a0.w*vs[cur][ 3];
      vacc += a1.x*vs[cur][ 4] + a1.y*vs[cur][ 5] + a1.z*vs[cur][ 6] + a1.w*vs[cur][ 7];
      vacc += a2.x*vs[cur][ 8] + a2.y*vs[cur][ 9] + a2.z*vs[cur][10] + a2.w*vs[cur][11];
      vacc += a3.x*vs[cur][12] + a3.y*vs[cur][13] + a3.z*vs[cur][14] + a3.w*vs[cur][15];
      vacc += bx;
    }
    Ps[cur ^ 1][i][j] = acc;
    if (j == 0) vs[cur ^ 1][i] = vacc;
    __syncthreads();
    cur ^= 1;
  }
  P_ws[(size_t)chunk * 256 + tid] = Ps[cur][i][j];
  if (tid < 16) v_ws[(size_t)chunk * DS + tid] = vs[cur][tid];
}

// ---------------------------------------------------------------------------
// K3: serial boundary scan across chunks (8 batches x 16 lanes = 128 thr,
// one block).  Writes the ENTERING state of every chunk.
// ---------------------------------------------------------------------------
__global__ __launch_bounds__(128) void k3_boundary(
    const float* __restrict__ P_ws, const float* __restrict__ v_ws,
    float* __restrict__ hb_ws)
{
  const int tid = threadIdx.x;
  const int b = tid >> 4;
  const int r = tid & 15;
  float h = 0.f;

  const float4* Pr = (const float4*)&P_ws[(size_t)(b * NCH) * 256 + r * 16];
  float4 c0 = Pr[0], c1 = Pr[1], c2 = Pr[2], c3 = Pr[3];
  float vc = v_ws[(size_t)(b * NCH) * DS + r];

  for (int c = 0; c < NCH; ++c) {
    const int chunk = b * NCH + c;
    float4 n0 = c0, n1 = c1, n2 = c2, n3 = c3; float nv = 0.f;
    if (c < NCH - 1) {
      const float4* Pn = (const float4*)&P_ws[(size_t)(chunk + 1) * 256 + r * 16];
      n0 = Pn[0]; n1 = Pn[1]; n2 = Pn[2]; n3 = Pn[3];
      nv = v_ws[(size_t)(chunk + 1) * DS + r];
    }
    hb_ws[(size_t)chunk * DS + r] = h;
    float acc = vc;
    acc += c0.x*__shfl(h, 0,16) + c0.y*__shfl(h, 1,16) + c0.z*__shfl(h, 2,16) + c0.w*__shfl(h, 3,16);
    acc += c1.x*__shfl(h, 4,16) + c1.y*__shfl(h, 5,16) + c1.z*__shfl(h, 6,16) + c1.w*__shfl(h, 7,16);
    acc += c2.x*__shfl(h, 8,16) + c2.y*__shfl(h, 9,16) + c2.z*__shfl(h,10,16) + c2.w*__shfl(h,11,16);
    acc += c3.x*__shfl(h,12,16) + c3.y*__shfl(h,13,16) + c3.z*__shfl(h,14,16) + c3.w*__shfl(h,15,16);
    h = acc;
    c0 = n0; c1 = n1; c2 = n2; c3 = n3; vc = nv;
  }
}

// ---------------------------------------------------------------------------
// K4: replay scan within each chunk from its boundary state; emit all h_t.
// 64 threads = 4 groups of 16 lanes, one chunk per group. 4-deep prefetch.
// ---------------------------------------------------------------------------
__global__ __launch_bounds__(64) void k4_hs(
    const float* __restrict__ A_ws, const float* __restrict__ Bx_ws,
    const float* __restrict__ hb_ws, float* __restrict__ hs_ws)
{
  const int tid = threadIdx.x;
  const int g = tid >> 4;
  const int r = tid & 15;
  const int chunk = blockIdx.x * 4 + g;
  const int tbase = chunk * CHUNK;

  float h = hb_ws[(size_t)chunk * DS + r];
  float4 pa[4][4];
  float pbx[4];
  #pragma unroll
  for (int s = 0; s < 4; ++s) {
    const float4* Arow = (const float4*)&A_ws[(size_t)(tbase + s) * 256 + r * 16];
    pa[s][0] = Arow[0]; pa[s][1] = Arow[1]; pa[s][2] = Arow[2]; pa[s][3] = Arow[3];
    pbx[s] = Bx_ws[(size_t)(tbase + s) * DS + r];
  }

  for (int t = 0; t < CHUNK; t += 4) {
    #pragma unroll
    for (int u = 0; u < 4; ++u) {
      const int tt = t + u;
      float4 q0 = pa[u][0], q1 = pa[u][1], q2 = pa[u][2], q3 = pa[u][3];
      float acc = pbx[u];
      if (tt + 4 < CHUNK) {
        const float4* Arow = (const float4*)&A_ws[(size_t)(tbase + tt + 4) * 256 + r * 16];
        pa[u][0] = Arow[0]; pa[u][1] = Arow[1]; pa[u][2] = Arow[2]; pa[u][3] = Arow[3];
        pbx[u] = Bx_ws[(size_t)(tbase + tt + 4) * DS + r];
      }
      acc += q0.x*__shfl(h, 0,16) + q0.y*__shfl(h, 1,16) + q0.z*__shfl(h, 2,16) + q0.w*__shfl(h, 3,16);
      acc += q1.x*__shfl(h, 4,16) + q1.y*__shfl(h, 5,16) + q1.z*__shfl(h, 6,16) + q1.w*__shfl(h, 7,16);
      acc += q2.x*__shfl(h, 8,16) + q2.y*__shfl(h, 9,16) + q2.z*__shfl(h,10,16) + q2.w*__shfl(h,11,16);
      acc += q3.x*__shfl(h,12,16) + q3.y*__shfl(h,13,16) + q3.z*__shfl(h,14,16) + q3.w*__shfl(h,15,16);
      hs_ws[(size_t)(tbase + tt) * DS + r] = acc;
      h = acc;
    }
  }
}

// ---------------------------------------------------------------------------
// K5: lane = timestep, x/h rows in registers.  Grid 1024: tile = blk>>1,
// dh = blk&1.  Wave w owns d0 = dh*32 + w*8 (8 cols).  Per n: z_d = sum_e
// x_e W[e,n,d] then acc_d += h_n z_d.  No LDS, no barriers.
// ---------------------------------------------------------------------------
__global__ __launch_bounds__(256, 4) void k5_out(
    const float* __restrict__ x,
    const float* __restrict__ WC, const float* __restrict__ bC,
    const float* __restrict__ hs_ws, float* __restrict__ out)
{
  const int tid  = threadIdx.x;
  const int L    = tid & 63;
  const int w    = __builtin_amdgcn_readfirstlane(tid >> 6);
  const int tile = blockIdx.x >> 1;
  const int dh   = blockIdx.x & 1;
  const int d0   = dh * 32 + w * 8;
  const int tt   = tile * 64 + L;

  float xr[64];
  {
    const float4* xg = (const float4*)(x + (size_t)tt * DM);
    #pragma unroll
    for (int i = 0; i < 16; ++i) {
      float4 v = xg[i];
      xr[4*i+0] = v.x; xr[4*i+1] = v.y; xr[4*i+2] = v.z; xr[4*i+3] = v.w;
    }
  }
  float hr[16];
  {
    const float4* hg = (const float4*)(hs_ws + (size_t)tt * DS);
    #pragma unroll
    for (int i = 0; i < 4; ++i) {
      float4 v = hg[i];
      hr[4*i+0] = v.x; hr[4*i+1] = v.y; hr[4*i+2] = v.z; hr[4*i+3] = v.w;
    }
  }

  float acc[8];
  #pragma unroll
  for (int k = 0; k < 8; ++k) acc[k] = 0.f;

  // bias: acc_d = sum_n h_n bC[n,d]
  #pragma unroll
  for (int n = 0; n < 16; ++n) {
    const float* bc = bC + n * 64 + d0;         // uniform
    #pragma unroll
    for (int k = 0; k < 8; ++k) acc[k] = fmaf(hr[n], bc[k], acc[k]);
  }

  #pragma unroll 1
  for (int n = 0; n < 16; ++n) {
    float z[8];
    #pragma unroll
    for (int k = 0; k < 8; ++k) z[k] = 0.f;
    #pragma unroll 8
    for (int e = 0; e < 64; ++e) {
      const float* wr = WC + e * 1024 + n * 64 + d0;  // uniform -> s_load
      const float xe = xr[e];
      #pragma unroll
      for (int k = 0; k < 8; ++k) z[k] = fmaf(xe, wr[k], z[k]);
    }
    #pragma unroll
    for (int k = 0; k < 8; ++k) acc[k] = fmaf(hr[n], z[k], acc[k]);
  }

  float* dst = out + (size_t)tt * DM + d0;
  ((float4*)dst)[0] = make_float4(acc[0], acc[1], acc[2], acc[3]);
  ((float4*)dst)[1] = make_float4(acc[4], acc[5], acc[6], acc[7]);
}

// ---------------------------------------------------------------------------
extern "C" void kernel_launch(void* const* d_in, const int* in_sizes, int n_in,
                              void* d_out, int out_size, void* d_ws, size_t ws_size,
                              hipStream_t stream) {
  const float* x  = (const float*)d_in[0];
  const float* WA = (const float*)d_in[1];
  const float* bA = (const float*)d_in[2];
  const float* WB = (const float*)d_in[3];
  const float* bB = (const float*)d_in[4];
  const float* WC = (const float*)d_in[5];
  const float* bC = (const float*)d_in[6];
  float* out = (float*)d_out;

  float* ws    = (float*)d_ws;
  float* A_ws  = ws;                              // 32768*256
  float* Bx_ws = A_ws  + (size_t)BS * 256;        // 32768*16
  float* P_ws  = Bx_ws + (size_t)BS * DS;         // 1024*256
  float* v_ws  = P_ws  + (size_t)NCH_TOT * 256;   // 1024*16
  float* hb_ws = v_ws  + (size_t)NCH_TOT * DS;    // 1024*16
  float* hs_ws = hb_ws + (size_t)NCH_TOT * DS;    // 32768*16

  k1_params  <<<BS / 64 * 2, 256, 0, stream>>>(x, WA, bA, WB, bB, A_ws, Bx_ws);
  k2_chunk   <<<NCH_TOT,     256, 0, stream>>>(A_ws, Bx_ws, P_ws, v_ws);
  k3_boundary<<<1,           128, 0, stream>>>(P_ws, v_ws, hb_ws);
  k4_hs      <<<NCH_TOT / 4,  64, 0, stream>>>(A_ws, Bx_ws, hb_ws, hs_ws);
  k5_out     <<<BS / 64 * 2, 256, 0, stream>>>(x, WC, bC, hs_ws, out);
}

// Round 5
// 376.627 us; speedup vs baseline: 1.4175x; 1.4175x over previous
//
#include <hip/hip_runtime.h>

// Problem constants (B=8, S=4096, D=64, ds=16)
#define BATCH   8
#define SEQ     4096
#define DM      64
#define DS      16
#define BS      (BATCH*SEQ)      // 32768 timesteps
#define CHUNK   32               // scan chunk length
#define NCH     (SEQ/CHUNK)      // 128 chunks per batch
#define NCH_TOT (BATCH*NCH)      // 1024 chunks total

// ---------------------------------------------------------------------------
// K1: lane = timestep.  x tile staged in LDS; rolled e-loop does ONE
// ds_read_b32 per e; all register arrays statically indexed (full unroll).
// Weights wave-uniform -> s_load.  Grid 1024: tile = blk>>1, q = blk&1.
// Wave w: A j-cols [q*128+w*32,+32), Bx n = q*8+w*2+{0,1}.
// ---------------------------------------------------------------------------
__global__ void k1_params(
    const float* __restrict__ x,
    const float* __restrict__ WA, const float* __restrict__ bA,
    const float* __restrict__ WB, const float* __restrict__ bB,
    float* __restrict__ A_ws, float* __restrict__ Bx_ws)
{
  __shared__ float xs[64][65];   // +1 pad: column reads are 2-way (free)
  const int tid  = threadIdx.x;
  const int L    = tid & 63;
  const int w    = __builtin_amdgcn_readfirstlane(tid >> 6);
  const int tile = blockIdx.x >> 1;
  const int q    = blockIdx.x & 1;
  const int t0   = tile * 64;
  const int tt   = t0 + L;

  { // stage + transpose x tile (coalesced float4 in, scalar LDS out)
    const float4* xg = (const float4*)(x + (size_t)t0 * DM);
    #pragma unroll
    for (int i = 0; i < 4; ++i) {
      const int f4 = tid + 256 * i;
      float4 v = xg[f4];
      const int t = (4 * f4) >> 6;
      const int e = (4 * f4) & 63;
      xs[t][e] = v.x; xs[t][e + 1] = v.y; xs[t][e + 2] = v.z; xs[t][e + 3] = v.w;
    }
  }
  __syncthreads();

  // ---- A part: 32 j-cols in two 16-wide tiles ----
  #pragma unroll 1
  for (int jt = 0; jt < 2; ++jt) {
    const int jb = q * 128 + w * 32 + jt * 16;
    float acc[16];
    #pragma unroll
    for (int k = 0; k < 16; ++k) acc[k] = bA[jb + k];   // uniform s_load
    #pragma unroll 1
    for (int e = 0; e < 64; ++e) {
      const float xe = xs[L][e];                         // 1 ds_read_b32
      const float* wr = WA + e * 256 + jb;               // uniform
      #pragma unroll
      for (int k = 0; k < 16; ++k) acc[k] = fmaf(xe, wr[k], acc[k]);
    }
    float* dst = A_ws + (size_t)tt * 256 + jb;
    #pragma unroll
    for (int p = 0; p < 4; ++p)
      ((float4*)dst)[p] = make_float4(acc[4*p], acc[4*p+1], acc[4*p+2], acc[4*p+3]);
  }

  // ---- Bx part: y_d = b[n,d] + sum_e x_e W[e,n,d];  bx = sum_d x_d y_d ----
  #pragma unroll 1
  for (int nn = 0; nn < 2; ++nn) {
    const int n = q * 8 + w * 2 + nn;
    float y[64];
    {
      const float* bb = bB + n * 64;                     // uniform
      #pragma unroll
      for (int d = 0; d < 64; ++d) y[d] = bb[d];
    }
    #pragma unroll 1
    for (int e = 0; e < 64; ++e) {
      const float xe = xs[L][e];                         // 1 ds_read_b32
      const float* wr = WB + e * 1024 + n * 64;          // uniform
      #pragma unroll
      for (int d = 0; d < 64; ++d) y[d] = fmaf(xe, wr[d], y[d]);
    }
    float bp0 = 0.f, bp1 = 0.f, bp2 = 0.f, bp3 = 0.f;
    #pragma unroll
    for (int d = 0; d < 16; ++d) {                       // fully unrolled: static
      bp0 = fmaf(xs[L][4*d+0], y[4*d+0], bp0);
      bp1 = fmaf(xs[L][4*d+1], y[4*d+1], bp1);
      bp2 = fmaf(xs[L][4*d+2], y[4*d+2], bp2);
      bp3 = fmaf(xs[L][4*d+3], y[4*d+3], bp3);
    }
    Bx_ws[(size_t)tt * DS + n] = (bp0 + bp1) + (bp2 + bp3);
  }
}

// ---------------------------------------------------------------------------
// K2: per-chunk cumulative transition with ONE barrier per step.
// P/v double-buffered in LDS; A rows read from global (vmcnt, no barrier).
// 256 thr (thread = (i,j)), one block per chunk, grid 1024 -> 4 blocks/CU.
// ---------------------------------------------------------------------------
__global__ __launch_bounds__(256) void k2_chunk(
    const float* __restrict__ A_ws, const float* __restrict__ Bx_ws,
    float* __restrict__ P_ws, float* __restrict__ v_ws)
{
  __shared__ float Ps[2][16][17];   // +1 pad
  __shared__ float vs[2][16];
  const int tid = threadIdx.x;
  const int i = tid >> 4, j = tid & 15;
  const int chunk = blockIdx.x;
  const int tbase = chunk * CHUNK;

  Ps[0][i][j] = (i == j) ? 1.f : 0.f;
  if (tid < 16) vs[0][tid] = 0.f;
  __syncthreads();

  int cur = 0;
  for (int t = 0; t < CHUNK; ++t) {
    const float4* ar = (const float4*)(A_ws + (size_t)(tbase + t) * 256 + i * 16);
    float4 a0 = ar[0], a1 = ar[1], a2 = ar[2], a3 = ar[3];
    float bx = (j == 0) ? Bx_ws[(size_t)(tbase + t) * DS + i] : 0.f;

    float acc;
    acc  = a0.x*Ps[cur][ 0][j] + a0.y*Ps[cur][ 1][j] + a0.z*Ps[cur][ 2][j] + a0.w*Ps[cur][ 3][j];
    acc += a1.x*Ps[cur][ 4][j] + a1.y*Ps[cur][ 5][j] + a1.z*Ps[cur][ 6][j] + a1.w*Ps[cur][ 7][j];
    acc += a2.x*Ps[cur][ 8][j] + a2.y*Ps[cur][ 9][j] + a2.z*Ps[cur][10][j] + a2.w*Ps[cur][11][j];
    acc += a3.x*Ps[cur][12][j] + a3.y*Ps[cur][13][j] + a3.z*Ps[cur][14][j] + a3.w*Ps[cur][15][j];
    float vacc = 0.f;
    if (j == 0) {
      vacc  = a0.x*vs[cur][ 0] + a0.y*vs[cur][ 1] + a0.z*vs[cur][ 2] + a0.w*vs[cur][ 3];
      vacc += a1.x*vs[cur][ 4] + a1.y*vs[cur][ 5] + a1.z*vs[cur][ 6] + a1.w*vs[cur][ 7];
      vacc += a2.x*vs[cur][ 8] + a2.y*vs[cur][ 9] + a2.z*vs[cur][10] + a2.w*vs[cur][11];
      vacc += a3.x*vs[cur][12] + a3.y*vs[cur][13] + a3.z*vs[cur][14] + a3.w*vs[cur][15];
      vacc += bx;
    }
    Ps[cur ^ 1][i][j] = acc;
    if (j == 0) vs[cur ^ 1][i] = vacc;
    __syncthreads();
    cur ^= 1;
  }
  P_ws[(size_t)chunk * 256 + tid] = Ps[cur][i][j];
  if (tid < 16) v_ws[(size_t)chunk * DS + tid] = vs[cur][tid];
}

// ---------------------------------------------------------------------------
// K3: serial boundary scan across chunks (8 batches x 16 lanes = 128 thr,
// one block).  Writes the ENTERING state of every chunk.
// ---------------------------------------------------------------------------
__global__ __launch_bounds__(128) void k3_boundary(
    const float* __restrict__ P_ws, const float* __restrict__ v_ws,
    float* __restrict__ hb_ws)
{
  const int tid = threadIdx.x;
  const int b = tid >> 4;
  const int r = tid & 15;
  float h = 0.f;

  const float4* Pr = (const float4*)&P_ws[(size_t)(b * NCH) * 256 + r * 16];
  float4 c0 = Pr[0], c1 = Pr[1], c2 = Pr[2], c3 = Pr[3];
  float vc = v_ws[(size_t)(b * NCH) * DS + r];

  for (int c = 0; c < NCH; ++c) {
    const int chunk = b * NCH + c;
    float4 n0 = c0, n1 = c1, n2 = c2, n3 = c3; float nv = 0.f;
    if (c < NCH - 1) {
      const float4* Pn = (const float4*)&P_ws[(size_t)(chunk + 1) * 256 + r * 16];
      n0 = Pn[0]; n1 = Pn[1]; n2 = Pn[2]; n3 = Pn[3];
      nv = v_ws[(size_t)(chunk + 1) * DS + r];
    }
    hb_ws[(size_t)chunk * DS + r] = h;
    float acc = vc;
    acc += c0.x*__shfl(h, 0,16) + c0.y*__shfl(h, 1,16) + c0.z*__shfl(h, 2,16) + c0.w*__shfl(h, 3,16);
    acc += c1.x*__shfl(h, 4,16) + c1.y*__shfl(h, 5,16) + c1.z*__shfl(h, 6,16) + c1.w*__shfl(h, 7,16);
    acc += c2.x*__shfl(h, 8,16) + c2.y*__shfl(h, 9,16) + c2.z*__shfl(h,10,16) + c2.w*__shfl(h,11,16);
    acc += c3.x*__shfl(h,12,16) + c3.y*__shfl(h,13,16) + c3.z*__shfl(h,14,16) + c3.w*__shfl(h,15,16);
    h = acc;
    c0 = n0; c1 = n1; c2 = n2; c3 = n3; vc = nv;
  }
}

// ---------------------------------------------------------------------------
// K4: replay scan within each chunk from its boundary state; emit all h_t.
// 64 threads = 4 groups of 16 lanes, one chunk per group. 4-deep prefetch.
// ---------------------------------------------------------------------------
__global__ __launch_bounds__(64) void k4_hs(
    const float* __restrict__ A_ws, const float* __restrict__ Bx_ws,
    const float* __restrict__ hb_ws, float* __restrict__ hs_ws)
{
  const int tid = threadIdx.x;
  const int g = tid >> 4;
  const int r = tid & 15;
  const int chunk = blockIdx.x * 4 + g;
  const int tbase = chunk * CHUNK;

  float h = hb_ws[(size_t)chunk * DS + r];
  float4 pa[4][4];
  float pbx[4];
  #pragma unroll
  for (int s = 0; s < 4; ++s) {
    const float4* Arow = (const float4*)&A_ws[(size_t)(tbase + s) * 256 + r * 16];
    pa[s][0] = Arow[0]; pa[s][1] = Arow[1]; pa[s][2] = Arow[2]; pa[s][3] = Arow[3];
    pbx[s] = Bx_ws[(size_t)(tbase + s) * DS + r];
  }

  for (int t = 0; t < CHUNK; t += 4) {
    #pragma unroll
    for (int u = 0; u < 4; ++u) {
      const int tt = t + u;
      float4 q0 = pa[u][0], q1 = pa[u][1], q2 = pa[u][2], q3 = pa[u][3];
      float acc = pbx[u];
      if (tt + 4 < CHUNK) {
        const float4* Arow = (const float4*)&A_ws[(size_t)(tbase + tt + 4) * 256 + r * 16];
        pa[u][0] = Arow[0]; pa[u][1] = Arow[1]; pa[u][2] = Arow[2]; pa[u][3] = Arow[3];
        pbx[u] = Bx_ws[(size_t)(tbase + tt + 4) * DS + r];
      }
      acc += q0.x*__shfl(h, 0,16) + q0.y*__shfl(h, 1,16) + q0.z*__shfl(h, 2,16) + q0.w*__shfl(h, 3,16);
      acc += q1.x*__shfl(h, 4,16) + q1.y*__shfl(h, 5,16) + q1.z*__shfl(h, 6,16) + q1.w*__shfl(h, 7,16);
      acc += q2.x*__shfl(h, 8,16) + q2.y*__shfl(h, 9,16) + q2.z*__shfl(h,10,16) + q2.w*__shfl(h,11,16);
      acc += q3.x*__shfl(h,12,16) + q3.y*__shfl(h,13,16) + q3.z*__shfl(h,14,16) + q3.w*__shfl(h,15,16);
      hs_ws[(size_t)(tbase + tt) * DS + r] = acc;
      h = acc;
    }
  }
}

// ---------------------------------------------------------------------------
// K5: lane = timestep.  out[t,d] = sum_e x_e * S_e[d],
// S_e[d] = sum_n h_n W[e,n,d]  (+ bias term sum_n h_n bC[n,d]).
// e rolled (1 ds_read_b32/e); n and d fully unrolled -> static regs.
// Grid 1024: tile = blk>>1, dh = blk&1; wave w owns d0 = dh*32 + w*8.
// ---------------------------------------------------------------------------
__global__ void k5_out(
    const float* __restrict__ x,
    const float* __restrict__ WC, const float* __restrict__ bC,
    const float* __restrict__ hs_ws, float* __restrict__ out)
{
  __shared__ float xs[64][65];
  const int tid  = threadIdx.x;
  const int L    = tid & 63;
  const int w    = __builtin_amdgcn_readfirstlane(tid >> 6);
  const int tile = blockIdx.x >> 1;
  const int dh   = blockIdx.x & 1;
  const int d0   = dh * 32 + w * 8;
  const int t0   = tile * 64;
  const int tt   = t0 + L;

  { // stage + transpose x tile
    const float4* xg = (const float4*)(x + (size_t)t0 * DM);
    #pragma unroll
    for (int i = 0; i < 4; ++i) {
      const int f4 = tid + 256 * i;
      float4 v = xg[f4];
      const int t = (4 * f4) >> 6;
      const int e = (4 * f4) & 63;
      xs[t][e] = v.x; xs[t][e + 1] = v.y; xs[t][e + 2] = v.z; xs[t][e + 3] = v.w;
    }
  }
  __syncthreads();

  float hr[16];
  {
    const float4* hg = (const float4*)(hs_ws + (size_t)tt * DS);
    #pragma unroll
    for (int i = 0; i < 4; ++i) {
      float4 v = hg[i];
      hr[4*i+0] = v.x; hr[4*i+1] = v.y; hr[4*i+2] = v.z; hr[4*i+3] = v.w;
    }
  }

  float acc[8];
  #pragma unroll
  for (int k = 0; k < 8; ++k) acc[k] = 0.f;

  // bias: acc_d = sum_n h_n bC[n,d]
  #pragma unroll
  for (int n = 0; n < 16; ++n) {
    const float* bc = bC + n * 64 + d0;              // uniform
    #pragma unroll
    for (int k = 0; k < 8; ++k) acc[k] = fmaf(hr[n], bc[k], acc[k]);
  }

  #pragma unroll 1
  for (int e = 0; e < 64; ++e) {
    const float xe = xs[L][e];                       // 1 ds_read_b32
    float S[8];
    #pragma unroll
    for (int k = 0; k < 8; ++k) S[k] = 0.f;
    #pragma unroll
    for (int n = 0; n < 16; ++n) {
      const float* wr = WC + e * 1024 + n * 64 + d0; // uniform -> s_load
      #pragma unroll
      for (int k = 0; k < 8; ++k) S[k] = fmaf(hr[n], wr[k], S[k]);
    }
    #pragma unroll
    for (int k = 0; k < 8; ++k) acc[k] = fmaf(xe, S[k], acc[k]);
  }

  float* dst = out + (size_t)tt * DM + d0;
  ((float4*)dst)[0] = make_float4(acc[0], acc[1], acc[2], acc[3]);
  ((float4*)dst)[1] = make_float4(acc[4], acc[5], acc[6], acc[7]);
}

// ---------------------------------------------------------------------------
extern "C" void kernel_launch(void* const* d_in, const int* in_sizes, int n_in,
                              void* d_out, int out_size, void* d_ws, size_t ws_size,
                              hipStream_t stream) {
  const float* x  = (const float*)d_in[0];
  const float* WA = (const float*)d_in[1];
  const float* bA = (const float*)d_in[2];
  const float* WB = (const float*)d_in[3];
  const float* bB = (const float*)d_in[4];
  const float* WC = (const float*)d_in[5];
  const float* bC = (const float*)d_in[6];
  float* out = (float*)d_out;

  float* ws    = (float*)d_ws;
  float* A_ws  = ws;                              // 32768*256
  float* Bx_ws = A_ws  + (size_t)BS * 256;        // 32768*16
  float* P_ws  = Bx_ws + (size_t)BS * DS;         // 1024*256
  float* v_ws  = P_ws  + (size_t)NCH_TOT * 256;   // 1024*16
  float* hb_ws = v_ws  + (size_t)NCH_TOT * DS;    // 1024*16
  float* hs_ws = hb_ws + (size_t)NCH_TOT * DS;    // 32768*16

  k1_params  <<<BS / 64 * 2, 256, 0, stream>>>(x, WA, bA, WB, bB, A_ws, Bx_ws);
  k2_chunk   <<<NCH_TOT,     256, 0, stream>>>(A_ws, Bx_ws, P_ws, v_ws);
  k3_boundary<<<1,           128, 0, stream>>>(P_ws, v_ws, hb_ws);
  k4_hs      <<<NCH_TOT / 4,  64, 0, stream>>>(A_ws, Bx_ws, hb_ws, hs_ws);
  k5_out     <<<BS / 64 * 2, 256, 0, stream>>>(x, WC, bC, hs_ws, out);
}